// Round 9
// baseline (197.921 us; speedup 1.0000x reference)
//
#include <hip/hip_runtime.h>

#define NNODES 100000
#define NREL 8
#define EMB 64
#define RN (NREL * NNODES)           // 800000 CSR segments (keys n*8+r)
#define YDIM (NREL * EMB)            // 512
#define NB_SCAN ((RN + 1023) / 1024) // 782 scan blocks
#define NSTRIPS (NNODES / 16)        // 6250, exact
#define G1B 625                      // gemm blocks; 10 strips per block, exact

typedef __attribute__((ext_vector_type(8))) short bf16x8;   // 8 bf16 (4 VGPRs)
typedef __attribute__((ext_vector_type(4))) float f32x4;

__device__ inline unsigned short f2bf(float f) {
    union { float f; unsigned u; } v; v.f = f;
    return (unsigned short)((v.u + 0x7FFFu + ((v.u >> 16) & 1u)) >> 16);  // RNE
}
__device__ inline float bf2f(unsigned short u) {
    union { unsigned u; float f; } v; v.u = ((unsigned)u) << 16; return v.f;
}

// ---------------------------------------------------------------------------
// K1: degree count per node-major key (n*8 + r)
// ---------------------------------------------------------------------------
__global__ void k_degree(const int* __restrict__ rows, int* __restrict__ deg, int E) {
    int e = blockIdx.x * blockDim.x + threadIdx.x;
    if (e < E) {
        int row = rows[e];
        int r = row / NNODES;            // magic-mul
        int n = row - r * NNODES;
        atomicAdd(&deg[n * NREL + r], 1);
    }
}

// ---------------------------------------------------------------------------
// Scan step 1: per-1024-chunk sums
// ---------------------------------------------------------------------------
__global__ void k_bsum(const int* __restrict__ deg, int* __restrict__ bsum) {
    int t = threadIdx.x;
    int base = blockIdx.x * 1024 + t * 4;
    int s = 0;
    if (base < RN) { int4 v = *reinterpret_cast<const int4*>(deg + base); s = v.x + v.y + v.z + v.w; }
#pragma unroll
    for (int d = 1; d < 64; d <<= 1) s += __shfl_xor(s, d);
    __shared__ int ws[4];
    if ((t & 63) == 0) ws[t >> 6] = s;
    __syncthreads();
    if (t == 0) bsum[blockIdx.x] = ws[0] + ws[1] + ws[2] + ws[3];
}

// ---------------------------------------------------------------------------
// Scan step 2: exclusive scan of the 782 chunk sums (single block)
// ---------------------------------------------------------------------------
__global__ void k_scan_mid(const int* __restrict__ bsum, int* __restrict__ boff) {
    __shared__ int tmp[1024];
    int t = threadIdx.x;
    int v0 = (t < NB_SCAN) ? bsum[t] : 0;
    tmp[t] = v0;
    __syncthreads();
    for (int d = 1; d < 1024; d <<= 1) {
        int u = (t >= d) ? tmp[t - d] : 0;
        __syncthreads();
        tmp[t] += u;
        __syncthreads();
    }
    if (t < NB_SCAN) boff[t] = tmp[t] - v0;   // exclusive
}

// ---------------------------------------------------------------------------
// Scan step 3: full exclusive row_ptr (start offsets)
// ---------------------------------------------------------------------------
__global__ void k_rowptr(const int* __restrict__ deg, const int* __restrict__ boff,
                         int* __restrict__ row_ptr) {
    int t = threadIdx.x;
    int base = blockIdx.x * 1024 + t * 4;
    int4 v = {0, 0, 0, 0};
    if (base < RN) v = *reinterpret_cast<const int4*>(deg + base);
    int s = v.x + v.y + v.z + v.w;
    int lane = t & 63;
    int inc = s;
#pragma unroll
    for (int d = 1; d < 64; d <<= 1) { int u = __shfl_up(inc, d); if (lane >= d) inc += u; }
    __shared__ int ws[4];
    if (lane == 63) ws[t >> 6] = inc;
    __syncthreads();
    int off = boff[blockIdx.x];
    int wid = t >> 6;
    for (int i = 0; i < wid; ++i) off += ws[i];
    int run = off + inc - s;                  // exclusive prefix for this thread
    if (base < RN) {
        int4 o;
        o.x = run; run += v.x;
        o.y = run; run += v.y;
        o.z = run; run += v.z;
        o.w = run;
        *reinterpret_cast<int4*>(row_ptr + base) = o;
    }
}

// ---------------------------------------------------------------------------
// FUSED sort + GEMM1 (independent work, complementary bottlenecks).
// Blocks [0, G1B):   GEMM1  y[c, r*64+f] = sum_k x[c,k]*W[r,k,f], 10 strips.
// Blocks [G1B, ...): counting-sort scatter keys[p] = c*8+r (4B payload; inv
//                    is reconstructed in gather from deg). Mutates rptr to
//                    segment ENDs.
// ---------------------------------------------------------------------------
__global__ __launch_bounds__(512) void k_sortgemm(const float* __restrict__ x,
                                                  const float* __restrict__ W,
                                                  unsigned short* __restrict__ y,
                                                  const int* __restrict__ rows,
                                                  const int* __restrict__ cols,
                                                  int* __restrict__ rptr,
                                                  int* __restrict__ keys, int E) {
    __shared__ char tile[16384];           // bf16 [16][512], swizzled (gemm only)
    const int tid = threadIdx.x;

    if (blockIdx.x >= G1B) {
        // ---------------- sort part ----------------
        int e = (blockIdx.x - G1B) * 512 + tid;
        if (e < E) {
            int row = rows[e];
            int r = row / NNODES;
            int n = row - r * NNODES;
            int p = atomicAdd(&rptr[n * NREL + r], 1);
            keys[p] = cols[e] * NREL + r;
        }
        return;
    }

    // ---------------- gemm part ----------------
    const int lane = tid & 63;
    const int rel  = tid >> 6;             // wave id = relation
    const int fl   = lane & 15;            // A row (f_local) == B col (c_local)
    const int kgrp = lane >> 4;            // k-group 0..3

    // A fragments: wfrag[ft][ks][j] = W[rel][ks*32 + kgrp*8 + j][ft*16 + fl]
    bf16x8 wfrag[4][2];
#pragma unroll
    for (int ft = 0; ft < 4; ++ft)
#pragma unroll
        for (int ks = 0; ks < 2; ++ks) {
            const float* wp = W + ((size_t)rel * EMB + ks * 32 + kgrp * 8) * EMB
                              + ft * 16 + fl;
            bf16x8 a;
#pragma unroll
            for (int j = 0; j < 8; ++j) a[j] = (short)f2bf(wp[(size_t)j * EMB]);
            wfrag[ft][ks] = a;
        }

    const int wbase = (fl << 10) + (rel << 7) + (kgrp << 3);
    const int wswz  = (fl & 7) << 4;

    for (int strip = blockIdx.x; strip < NSTRIPS; strip += G1B) {
        const int c = strip * 16 + fl;
        const float* xp = x + (size_t)c * EMB + kgrp * 8;
        f32x4 x0 = *reinterpret_cast<const f32x4*>(xp);        // ks=0
        f32x4 x1 = *reinterpret_cast<const f32x4*>(xp + 4);
        f32x4 x2 = *reinterpret_cast<const f32x4*>(xp + 32);   // ks=1
        f32x4 x3 = *reinterpret_cast<const f32x4*>(xp + 36);
        bf16x8 B0, B1;
#pragma unroll
        for (int j = 0; j < 4; ++j) {
            B0[j] = (short)f2bf(x0[j]);  B0[j + 4] = (short)f2bf(x1[j]);
            B1[j] = (short)f2bf(x2[j]);  B1[j + 4] = (short)f2bf(x3[j]);
        }

        f32x4 acc[4] = {f32x4{}, f32x4{}, f32x4{}, f32x4{}};
#pragma unroll
        for (int ft = 0; ft < 4; ++ft) {
            acc[ft] = __builtin_amdgcn_mfma_f32_16x16x32_bf16(wfrag[ft][0], B0, acc[ft], 0, 0, 0);
            acc[ft] = __builtin_amdgcn_mfma_f32_16x16x32_bf16(wfrag[ft][1], B1, acc[ft], 0, 0, 0);
        }

        // D[f][c] -> LDS bf16 tile at [c_local=fl][f_glob=rel*64+ft*16+kgrp*4+i]
#pragma unroll
        for (int ft = 0; ft < 4; ++ft) {
            ushort4 o;
            o.x = f2bf(acc[ft][0]); o.y = f2bf(acc[ft][1]);
            o.z = f2bf(acc[ft][2]); o.w = f2bf(acc[ft][3]);
            *reinterpret_cast<ushort4*>(tile + ((wbase + (ft << 5)) ^ wswz)) = o;
        }
        __syncthreads();

        // stream tile -> y, fully coalesced 16B/lane
#pragma unroll
        for (int h = 0; h < 2; ++h) {
            int u  = tid + h * 512;            // 16B unit 0..1023
            int cl = u >> 6;                   // c_local
            bf16x8 v = *reinterpret_cast<const bf16x8*>(tile + ((u << 4) ^ ((cl & 7) << 4)));
            *reinterpret_cast<bf16x8*>(y + (size_t)(strip * 16 + cl) * YDIM + ((u & 63) << 3)) = v;
        }
        __syncthreads();
    }
}

// ---------------------------------------------------------------------------
// Gather: one wave per node; lane = output dim f. inv8 = rcp(deg[n*8+lane&7])
// built once per node; per edge: readlane(key) -> scalar y-row, r = key&7 ->
// readlane(inv8, r); acc = fmaf(inv, y[key*64+lane], acc). 8-deep MLP batches.
// Writes final out = relu(acc) directly.
// ---------------------------------------------------------------------------
__global__ void k_gather(const int* __restrict__ rptr, const int* __restrict__ keys,
                         const int* __restrict__ deg,
                         const unsigned short* __restrict__ yb, float* __restrict__ out) {
    int n = blockIdx.x * (blockDim.x >> 6) + (threadIdx.x >> 6);
    if (n >= NNODES) return;
    const int lane = threadIdx.x & 63;

    int s = (n == 0) ? 0 : rptr[n * NREL - 1];     // wave-uniform broadcast loads
    int e = rptr[n * NREL + NREL - 1];

    // per-lane inv table: lane L holds 1/deg[n*8 + (L&7)] (inf if deg==0 --
    // only read for relations that HAVE edges, where deg>=1)
    float inv8 = __builtin_amdgcn_rcpf((float)deg[n * NREL + (lane & 7)]);
    int inv8b = __float_as_int(inv8);

    float acc = 0.f;
    for (int c0 = s; c0 < e; c0 += 64) {
        int m = e - c0; if (m > 64) m = 64;
        int kv = (lane < m) ? keys[c0 + lane] : 0;
        for (int j0 = 0; j0 < m; j0 += 8) {
#pragma unroll
            for (int u = 0; u < 8; ++u) {
                int j  = j0 + u;
                int jc = j < m ? j : 0;                         // uniform clamp
                int sp = __builtin_amdgcn_readlane(kv, jc);     // scalar y-row (c*8+r)
                int ib = __builtin_amdgcn_readlane(inv8b, sp & 7);
                float si = (j < m) ? __int_as_float(ib) : 0.f;  // dead edge -> *0
                float v  = bf2f(yb[(size_t)sp * EMB + lane]);
                acc = fmaf(si, v, acc);
            }
        }
    }
    out[(size_t)n * EMB + lane] = fmaxf(acc, 0.f);
}

// ---------------------------------------------------------------------------
extern "C" void kernel_launch(void* const* d_in, const int* in_sizes, int n_in,
                              void* d_out, int out_size, void* d_ws, size_t ws_size,
                              hipStream_t stream) {
    const float* x    = (const float*)d_in[0];
    const float* w    = (const float*)d_in[1];
    const int*   rows = (const int*)d_in[2];   // JAX x64-disabled -> int32
    const int*   cols = (const int*)d_in[3];
    float*       out  = (float*)d_out;
    int E = in_sizes[2];

    char* ws = (char*)d_ws;
    int*            deg   = (int*)(ws);                       // 3.2 MB
    int*            rptr  = (int*)(ws + 3200000);             // 3.2 MB
    int*            bsum  = (int*)(ws + 6400000);             // 4 KB
    int*            boff  = (int*)(ws + 6404096);             // 4 KB
    int*            keys  = (int*)(ws + 6408192);             // 4 MB
    unsigned short* y     = (unsigned short*)(ws + 10408192); // 102.4 MB

    hipMemsetAsync(deg, 0, (size_t)RN * sizeof(int), stream);

    k_degree<<<(E + 255) / 256, 256, 0, stream>>>(rows, deg, E);
    k_bsum<<<NB_SCAN, 256, 0, stream>>>(deg, bsum);
    k_scan_mid<<<1, 1024, 0, stream>>>(bsum, boff);
    k_rowptr<<<NB_SCAN, 256, 0, stream>>>(deg, boff, rptr);

    int sortBlocks = (E + 511) / 512;
    k_sortgemm<<<G1B + sortBlocks, 512, 0, stream>>>(x, w, y, rows, cols, rptr, keys, E);
    k_gather<<<(NNODES + 3) / 4, 256, 0, stream>>>(rptr, keys, deg, y, out);
}

// Round 10
// 181.934 us; speedup vs baseline: 1.0879x; 1.0879x over previous
//
#include <hip/hip_runtime.h>

#define NNODES 100000
#define NREL 8
#define EMB 64
#define RN (NREL * NNODES)           // 800000 CSR segments (keys n*8+r)
#define YDIM (NREL * EMB)            // 512
#define NB_SCAN ((RN + 1023) / 1024) // 782 scan blocks
#define NSTRIPS (NNODES / 16)        // 6250, exact
#define G1_BLOCKS 1250               // 5 strips per block, exact
#define NSLICE (NNODES / 8)          // 12500 nodes per XCD slice

typedef __attribute__((ext_vector_type(8))) short bf16x8;   // 8 bf16 (4 VGPRs)
typedef __attribute__((ext_vector_type(4))) float f32x4;

__device__ inline unsigned short f2bf(float f) {
    union { float f; unsigned u; } v; v.f = f;
    return (unsigned short)((v.u + 0x7FFFu + ((v.u >> 16) & 1u)) >> 16);  // RNE
}
__device__ inline float bf2f(unsigned short u) {
    union { unsigned u; float f; } v; v.u = ((unsigned)u) << 16; return v.f;
}

// ---------------------------------------------------------------------------
// K1: degree count per node-major key (n*8 + r), XCD-sliced.
// Group g = blockIdx&7 (round-robin XCD mapping heuristic) streams all rows
// but only counts edges in its node slice -> deg atomics stay L2-resident.
// ---------------------------------------------------------------------------
__global__ void k_degree(const int* __restrict__ rows, int* __restrict__ deg, int E) {
    const int g   = blockIdx.x & 7;
    const int bl  = blockIdx.x >> 3;               // 0..127
    const int nlo = g * NSLICE, nhi = nlo + NSLICE;
    for (int e = bl * 256 + threadIdx.x; e < E; e += 128 * 256) {
        int row = rows[e];
        int r = row / NNODES;                      // magic-mul
        int n = row - r * NNODES;
        if (n >= nlo && n < nhi) atomicAdd(&deg[n * NREL + r], 1);
    }
}

// ---------------------------------------------------------------------------
// Scan step 1: per-1024-chunk sums
// ---------------------------------------------------------------------------
__global__ void k_bsum(const int* __restrict__ deg, int* __restrict__ bsum) {
    int t = threadIdx.x;
    int base = blockIdx.x * 1024 + t * 4;
    int s = 0;
    if (base < RN) { int4 v = *reinterpret_cast<const int4*>(deg + base); s = v.x + v.y + v.z + v.w; }
#pragma unroll
    for (int d = 1; d < 64; d <<= 1) s += __shfl_xor(s, d);
    __shared__ int ws[4];
    if ((t & 63) == 0) ws[t >> 6] = s;
    __syncthreads();
    if (t == 0) bsum[blockIdx.x] = ws[0] + ws[1] + ws[2] + ws[3];
}

// ---------------------------------------------------------------------------
// Scan step 2: exclusive scan of the 782 chunk sums (single block)
// ---------------------------------------------------------------------------
__global__ void k_scan_mid(const int* __restrict__ bsum, int* __restrict__ boff) {
    __shared__ int tmp[1024];
    int t = threadIdx.x;
    int v0 = (t < NB_SCAN) ? bsum[t] : 0;
    tmp[t] = v0;
    __syncthreads();
    for (int d = 1; d < 1024; d <<= 1) {
        int u = (t >= d) ? tmp[t - d] : 0;
        __syncthreads();
        tmp[t] += u;
        __syncthreads();
    }
    if (t < NB_SCAN) boff[t] = tmp[t] - v0;   // exclusive
}

// ---------------------------------------------------------------------------
// Scan step 3: full exclusive row_ptr (start offsets)
// ---------------------------------------------------------------------------
__global__ void k_rowptr(const int* __restrict__ deg, const int* __restrict__ boff,
                         int* __restrict__ row_ptr) {
    int t = threadIdx.x;
    int base = blockIdx.x * 1024 + t * 4;
    int4 v = {0, 0, 0, 0};
    if (base < RN) v = *reinterpret_cast<const int4*>(deg + base);
    int s = v.x + v.y + v.z + v.w;
    int lane = t & 63;
    int inc = s;
#pragma unroll
    for (int d = 1; d < 64; d <<= 1) { int u = __shfl_up(inc, d); if (lane >= d) inc += u; }
    __shared__ int ws[4];
    if (lane == 63) ws[t >> 6] = inc;
    __syncthreads();
    int off = boff[blockIdx.x];
    int wid = t >> 6;
    for (int i = 0; i < wid; ++i) off += ws[i];
    int run = off + inc - s;                  // exclusive prefix for this thread
    if (base < RN) {
        int4 o;
        o.x = run; run += v.x;
        o.y = run; run += v.y;
        o.z = run; run += v.z;
        o.w = run;
        *reinterpret_cast<int4*>(row_ptr + base) = o;
    }
}

// ---------------------------------------------------------------------------
// Counting-sort scatter, XCD-sliced like k_degree: group g only scatters its
// node slice -> rptr cursor atomics (400KB) and keys window (512KB) stay in
// one XCD's L2; HBM write collapses to the final ~4MB writeback.
// Mutates row_ptr: afterwards row_ptr[key] == segment END.
// ---------------------------------------------------------------------------
__global__ void k_sort(const int* __restrict__ rows, const int* __restrict__ cols,
                       int* __restrict__ rptr, int* __restrict__ keys, int E) {
    const int g   = blockIdx.x & 7;
    const int bl  = blockIdx.x >> 3;
    const int nlo = g * NSLICE, nhi = nlo + NSLICE;
    for (int e = bl * 256 + threadIdx.x; e < E; e += 128 * 256) {
        int row = rows[e];
        int r = row / NNODES;
        int n = row - r * NNODES;
        if (n >= nlo && n < nhi) {
            int p = atomicAdd(&rptr[n * NREL + r], 1);
            keys[p] = cols[e] * NREL + r;
        }
    }
}

// ---------------------------------------------------------------------------
// GEMM1: y[c, r*64+f] = sum_k x[c,k] * W[r,k,f]   (bf16 MFMA 16x16x32, K=64)
// Swapped-operand form: D[f][c] tiles. A = W^T fragments (strip-invariant, 32
// VGPRs); B = x rows loaded directly from global (16B/lane contiguous).
// Epilogue: DOUBLE-BUFFERED 16KB LDS transpose tiles with a raw s_barrier +
// lgkmcnt-only wait -- global stores are never vmcnt-drained (the implicit
// __syncthreads drain was serializing the 100MB write stream).
// Block = 512 thr (8 waves); wave = one relation, 16 nodes/strip; 5 strips.
// ---------------------------------------------------------------------------
__global__ __launch_bounds__(512) void k_gemm1(const float* __restrict__ x,
                                               const float* __restrict__ W,
                                               unsigned short* __restrict__ y) {
    __shared__ char tile[2][16384];        // bf16 [16][512], swizzled, x2 buffers
    const int tid  = threadIdx.x;
    const int lane = tid & 63;
    const int rel  = tid >> 6;             // wave id = relation
    const int fl   = lane & 15;            // A row (f_local) == B col (c_local)
    const int kgrp = lane >> 4;            // k-group 0..3

    // A fragments: wfrag[ft][ks][j] = W[rel][ks*32 + kgrp*8 + j][ft*16 + fl]
    bf16x8 wfrag[4][2];
#pragma unroll
    for (int ft = 0; ft < 4; ++ft)
#pragma unroll
        for (int ks = 0; ks < 2; ++ks) {
            const float* wp = W + ((size_t)rel * EMB + ks * 32 + kgrp * 8) * EMB
                              + ft * 16 + fl;
            bf16x8 a;
#pragma unroll
            for (int j = 0; j < 8; ++j) a[j] = (short)f2bf(wp[(size_t)j * EMB]);
            wfrag[ft][ks] = a;
        }

    const int wbase = (fl << 10) + (rel << 7) + (kgrp << 3);
    const int wswz  = (fl & 7) << 4;
    int b = 0;

    for (int strip = blockIdx.x; strip < NSTRIPS; strip += G1_BLOCKS) {
        const int c = strip * 16 + fl;
        const float* xp = x + (size_t)c * EMB + kgrp * 8;
        f32x4 x0 = *reinterpret_cast<const f32x4*>(xp);        // ks=0
        f32x4 x1 = *reinterpret_cast<const f32x4*>(xp + 4);
        f32x4 x2 = *reinterpret_cast<const f32x4*>(xp + 32);   // ks=1
        f32x4 x3 = *reinterpret_cast<const f32x4*>(xp + 36);
        bf16x8 B0, B1;
#pragma unroll
        for (int j = 0; j < 4; ++j) {
            B0[j] = (short)f2bf(x0[j]);  B0[j + 4] = (short)f2bf(x1[j]);
            B1[j] = (short)f2bf(x2[j]);  B1[j + 4] = (short)f2bf(x3[j]);
        }

        f32x4 acc[4] = {f32x4{}, f32x4{}, f32x4{}, f32x4{}};
#pragma unroll
        for (int ft = 0; ft < 4; ++ft) {
            acc[ft] = __builtin_amdgcn_mfma_f32_16x16x32_bf16(wfrag[ft][0], B0, acc[ft], 0, 0, 0);
            acc[ft] = __builtin_amdgcn_mfma_f32_16x16x32_bf16(wfrag[ft][1], B1, acc[ft], 0, 0, 0);
        }

        // D[f][c] -> LDS bf16 tile at [c_local=fl][f_glob=rel*64+ft*16+kgrp*4+i]
        char* tb = tile[b];
#pragma unroll
        for (int ft = 0; ft < 4; ++ft) {
            ushort4 o;
            o.x = f2bf(acc[ft][0]); o.y = f2bf(acc[ft][1]);
            o.z = f2bf(acc[ft][2]); o.w = f2bf(acc[ft][3]);
            *reinterpret_cast<ushort4*>(tb + ((wbase + (ft << 5)) ^ wswz)) = o;
        }

        // raw barrier: wait LDS only, do NOT drain global stores (vmcnt)
        __builtin_amdgcn_sched_barrier(0);
        asm volatile("s_waitcnt lgkmcnt(0)" ::: "memory");
        __builtin_amdgcn_s_barrier();
        __builtin_amdgcn_sched_barrier(0);

        // stream tile -> y, fully coalesced 16B/lane, fire-and-forget
#pragma unroll
        for (int h = 0; h < 2; ++h) {
            int u  = tid + h * 512;            // 16B unit 0..1023
            int cl = u >> 6;                   // c_local
            bf16x8 v = *reinterpret_cast<const bf16x8*>(tb + ((u << 4) ^ ((cl & 7) << 4)));
            *reinterpret_cast<bf16x8*>(y + (size_t)(strip * 16 + cl) * YDIM + ((u & 63) << 3)) = v;
        }
        b ^= 1;   // buffer reuse at distance 2 is protected by the barrier chain
    }
}

// ---------------------------------------------------------------------------
// Gather: one wave per node; lane = output dim f. inv8 = rcp(deg[n*8+lane&7])
// built once per node; per edge: readlane(key) -> scalar y-row, r = key&7 ->
// readlane(inv8, r); acc = fmaf(inv, y[key*64+lane], acc). 8-deep MLP batches.
// Writes final out = relu(acc) directly.
// ---------------------------------------------------------------------------
__global__ void k_gather(const int* __restrict__ rptr, const int* __restrict__ keys,
                         const int* __restrict__ deg,
                         const unsigned short* __restrict__ yb, float* __restrict__ out) {
    int n = blockIdx.x * (blockDim.x >> 6) + (threadIdx.x >> 6);
    if (n >= NNODES) return;
    const int lane = threadIdx.x & 63;

    int s = (n == 0) ? 0 : rptr[n * NREL - 1];     // wave-uniform broadcast loads
    int e = rptr[n * NREL + NREL - 1];

    // per-lane inv table: lane L holds 1/deg[n*8 + (L&7)] (inf if deg==0 --
    // only read for relations that HAVE edges, where deg>=1)
    float inv8 = __builtin_amdgcn_rcpf((float)deg[n * NREL + (lane & 7)]);
    int inv8b = __float_as_int(inv8);

    float acc = 0.f;
    for (int c0 = s; c0 < e; c0 += 64) {
        int m = e - c0; if (m > 64) m = 64;
        int kv = (lane < m) ? keys[c0 + lane] : 0;
        for (int j0 = 0; j0 < m; j0 += 8) {
#pragma unroll
            for (int u = 0; u < 8; ++u) {
                int j  = j0 + u;
                int jc = j < m ? j : 0;                         // uniform clamp
                int sp = __builtin_amdgcn_readlane(kv, jc);     // scalar y-row (c*8+r)
                int ib = __builtin_amdgcn_readlane(inv8b, sp & 7);
                float si = (j < m) ? __int_as_float(ib) : 0.f;  // dead edge -> *0
                float v  = bf2f(yb[(size_t)sp * EMB + lane]);
                acc = fmaf(si, v, acc);
            }
        }
    }
    out[(size_t)n * EMB + lane] = fmaxf(acc, 0.f);
}

// ---------------------------------------------------------------------------
extern "C" void kernel_launch(void* const* d_in, const int* in_sizes, int n_in,
                              void* d_out, int out_size, void* d_ws, size_t ws_size,
                              hipStream_t stream) {
    const float* x    = (const float*)d_in[0];
    const float* w    = (const float*)d_in[1];
    const int*   rows = (const int*)d_in[2];   // JAX x64-disabled -> int32
    const int*   cols = (const int*)d_in[3];
    float*       out  = (float*)d_out;
    int E = in_sizes[2];

    char* ws = (char*)d_ws;
    int*            deg   = (int*)(ws);                       // 3.2 MB
    int*            rptr  = (int*)(ws + 3200000);             // 3.2 MB
    int*            bsum  = (int*)(ws + 6400000);             // 4 KB
    int*            boff  = (int*)(ws + 6404096);             // 4 KB
    int*            keys  = (int*)(ws + 6408192);             // 4 MB
    unsigned short* y     = (unsigned short*)(ws + 10408192); // 102.4 MB

    hipMemsetAsync(deg, 0, (size_t)RN * sizeof(int), stream);

    k_degree<<<1024, 256, 0, stream>>>(rows, deg, E);
    k_bsum<<<NB_SCAN, 256, 0, stream>>>(deg, bsum);
    k_scan_mid<<<1, 1024, 0, stream>>>(bsum, boff);
    k_rowptr<<<NB_SCAN, 256, 0, stream>>>(deg, boff, rptr);
    k_sort<<<1024, 256, 0, stream>>>(rows, cols, rptr, keys, E);
    k_gemm1<<<G1_BLOCKS, 512, 0, stream>>>(x, w, y);
    k_gather<<<(NNODES + 3) / 4, 256, 0, stream>>>(rptr, keys, deg, y, out);
}